// Round 4
// baseline (1761.385 us; speedup 1.0000x reference)
//
#include <hip/hip_runtime.h>

#define BATCH   4
#define NPTS    4096
#define MPTS    4096
#define NSTEPS  16
#define ICP_TOL 1e-6f

#define TPB         256
#define NBLOCKS     512      // 128 blocks/batch x 4; EXACTLY 2 blocks/CU co-resident
#define BLK_PER_B   128
// LDS: 4096*16 B targets = 64 KB (+ ~1 KB misc) -> 2 blocks/CU (133 KB <= 160 KB)
// VGPR: forced <=128 by __launch_bounds__(256,2) -> 2 blocks/CU by regs too.

// ---------- double-precision 3x3 Kabsch (verified rounds 1/3) ----------

__device__ inline void normalize3d(double v[3]) {
    double n = sqrt(v[0]*v[0] + v[1]*v[1] + v[2]*v[2]);
    double inv = (n > 1e-300) ? 1.0 / n : 0.0;
    v[0] *= inv; v[1] *= inv; v[2] *= inv;
}

__device__ inline void cross3d(const double a[3], const double b[3], double c[3]) {
    c[0] = a[1]*b[2] - a[2]*b[1];
    c[1] = a[2]*b[0] - a[0]*b[2];
    c[2] = a[0]*b[1] - a[1]*b[0];
}

__device__ inline void eigvec_from_product(const double K[3][3], double la, double lb, double v[3]) {
    double A[3][3], Bm[3][3], C[3][3];
    for (int i = 0; i < 3; i++)
        for (int j = 0; j < 3; j++) {
            A[i][j]  = K[i][j] - ((i == j) ? la : 0.0);
            Bm[i][j] = K[i][j] - ((i == j) ? lb : 0.0);
        }
    for (int i = 0; i < 3; i++)
        for (int j = 0; j < 3; j++) {
            double s = 0.0;
            for (int k = 0; k < 3; k++) s += A[i][k] * Bm[k][j];
            C[i][j] = s;
        }
    int best = 0; double bn = -1.0;
    for (int c = 0; c < 3; c++) {
        double n2 = C[0][c]*C[0][c] + C[1][c]*C[1][c] + C[2][c]*C[2][c];
        if (n2 > bn) { bn = n2; best = c; }
    }
    if (bn > 1e-280) {
        double inv = 1.0 / sqrt(bn);
        v[0] = C[0][best]*inv; v[1] = C[1][best]*inv; v[2] = C[2][best]*inv;
    } else {
        v[0] = 1.0; v[1] = 0.0; v[2] = 0.0;
    }
}

__device__ inline void kabsch_from_sums(const double S[16], double R[3][3], double t[3]) {
    const double inv_n = 1.0 / (double)NPTS;
    double cs[3] = { S[0]*inv_n, S[1]*inv_n, S[2]*inv_n };
    double ct[3] = { S[3]*inv_n, S[4]*inv_n, S[5]*inv_n };
    double H[3][3];
    for (int i = 0; i < 3; i++)
        for (int j = 0; j < 3; j++)
            H[i][j] = S[6 + 3*i + j] - S[i]*S[3 + j]*inv_n;

    double K[3][3];
    for (int i = 0; i < 3; i++)
        for (int j = 0; j < 3; j++) {
            double s = 0.0;
            for (int k = 0; k < 3; k++) s += H[k][i]*H[k][j];
            K[i][j] = s;
        }

    double q = (K[0][0] + K[1][1] + K[2][2]) / 3.0;
    double p1 = K[0][1]*K[0][1] + K[0][2]*K[0][2] + K[1][2]*K[1][2];
    double a00 = K[0][0]-q, a11 = K[1][1]-q, a22 = K[2][2]-q;
    double p2 = a00*a00 + a11*a11 + a22*a22 + 2.0*p1;
    double p = sqrt(p2 / 6.0);
    double l1, l2, l3;
    if (p < 1e-150) {
        l1 = l2 = l3 = q;
    } else {
        double ip = 1.0 / p;
        double b00 = a00*ip, b01 = K[0][1]*ip, b02 = K[0][2]*ip;
        double b11 = a11*ip, b12 = K[1][2]*ip, b22 = a22*ip;
        double detB = b00*(b11*b22 - b12*b12)
                    - b01*(b01*b22 - b12*b02)
                    + b02*(b01*b12 - b11*b02);
        double r = 0.5 * detB;
        r = r < -1.0 ? -1.0 : (r > 1.0 ? 1.0 : r);
        double phi = acos(r) / 3.0;
        l1 = q + 2.0*p*cos(phi);
        l3 = q + 2.0*p*cos(phi + 2.0943951023931953);
        l2 = 3.0*q - l1 - l3;
    }

    double v1[3], v2[3], v3[3];
    eigvec_from_product(K, l2, l3, v1);
    eigvec_from_product(K, l1, l3, v2);
    double d12 = v1[0]*v2[0] + v1[1]*v2[1] + v1[2]*v2[2];
    for (int i = 0; i < 3; i++) v2[i] -= d12*v1[i];
    normalize3d(v2);
    cross3d(v1, v2, v3);

    double u1[3], u2[3], u3[3];
    for (int i = 0; i < 3; i++) u1[i] = H[i][0]*v1[0] + H[i][1]*v1[1] + H[i][2]*v1[2];
    normalize3d(u1);
    for (int i = 0; i < 3; i++) u2[i] = H[i][0]*v2[0] + H[i][1]*v2[1] + H[i][2]*v2[2];
    double du = u1[0]*u2[0] + u1[1]*u2[1] + u1[2]*u2[2];
    for (int i = 0; i < 3; i++) u2[i] -= du*u1[i];
    normalize3d(u2);
    cross3d(u1, u2, u3);

    for (int i = 0; i < 3; i++)
        for (int j = 0; j < 3; j++)
            R[i][j] = v1[i]*u1[j] + v2[i]*u2[j] + v3[i]*u3[j];
    for (int i = 0; i < 3; i++)
        t[i] = ct[i] - (R[i][0]*cs[0] + R[i][1]*cs[1] + R[i][2]*cs[2]);
}

// ------------------------------- kernels -------------------------------

__global__ void k_init(float* __restrict__ errlast, int* __restrict__ done_g,
                       unsigned int* __restrict__ ticket, unsigned int* __restrict__ release_g) {
    int tid = threadIdx.x;
    if (tid < BATCH) errlast[tid] = 0.0f;
    if (tid == 0) { *done_g = 0; *ticket = 0u; *release_g = 0u; }
}

// Single persistent kernel. Per-step grid barrier via monotonic ticket:
// the LAST arriving block (election) reduces partials, checks convergence,
// runs Kabsch, writes Rt/done, bumps release; all blocks spin on release.
__global__ __launch_bounds__(TPB, 2)
void k_icp(const float* __restrict__ src, const float* __restrict__ tgt,
           float* __restrict__ out, double* __restrict__ part_g,
           float* __restrict__ Rt_g, float* __restrict__ errlast,
           int* __restrict__ done_g, unsigned int* __restrict__ ticket,
           unsigned int* __restrict__ release_g) {
    __shared__ float4 t4c[MPTS];         // 64 KB: (x,y,z, 0.5*|t|^2), resident all steps
    __shared__ double pmem[4][16];       // per-wave partials
    __shared__ double Ssh[4][16];        // election block: per-batch sums
    __shared__ int    islast_sh, convsh;

    const int bid  = blockIdx.x;
    const int b    = bid >> 7;
    const int lb   = bid & (BLK_PER_B - 1);
    const int tid  = threadIdx.x;
    const int w    = tid >> 6;           // wave 0..3 owns 8 source points
    const int lane = tid & 63;

    const float* tgb = tgt + (size_t)b * MPTS * 3;
    const float* spb = src + ((size_t)b * NPTS + lb * 32 + w * 8) * 3;

    // ---- stage ALL targets into LDS once (reused by all 16 steps) ----
    for (int i = tid; i < MPTS; i += TPB) {
        float x = tgb[3*i], y = tgb[3*i+1], z = tgb[3*i+2];
        t4c[i] = make_float4(x, y, z, 0.5f*(x*x + y*y + z*z));
    }

    // own points: orig (for final Kabsch) + current, replicated across lanes
    float ox[8], oy[8], oz[8], px[8], py[8], pz[8];
    #pragma unroll
    for (int k = 0; k < 8; k++) {
        ox[k] = spb[3*k+0]; oy[k] = spb[3*k+1]; oz[k] = spb[3*k+2];
        px[k] = ox[k]; py[k] = oy[k]; pz[k] = oz[k];
    }
    __syncthreads();

    unsigned int gen = 0;

    for (int s = 0; s < NSTEPS; ++s) {
        // ---- 1-NN scan: score = 0.5|t|^2 - p.t  (d2 = |p|^2 + 2*score) ----
        float bs[8]; int bm[8];
        #pragma unroll
        for (int k = 0; k < 8; k++) { bs[k] = 1e30f; bm[k] = 0; }

        #pragma unroll 4
        for (int j = 0; j < MPTS/64; ++j) {
            int ml = (j << 6) | lane;
            float4 T = t4c[ml];
            #pragma unroll
            for (int k = 0; k < 8; k++) {
                float sc = __fmaf_rn(-px[k], T.x, T.w);
                sc = __fmaf_rn(-py[k], T.y, sc);
                sc = __fmaf_rn(-pz[k], T.z, sc);
                if (sc < bs[k]) { bs[k] = sc; bm[k] = ml; }   // first-min per lane
            }
        }
        // full-wave butterfly argmin, exact first-min (smallest index) tie rule
        #pragma unroll
        for (int off = 32; off >= 1; off >>= 1) {
            #pragma unroll
            for (int k = 0; k < 8; k++) {
                float os = __shfl_xor(bs[k], off);
                int   om = __shfl_xor(bm[k], off);
                if (os < bs[k] || (os == bs[k] && om < bm[k])) { bs[k] = os; bm[k] = om; }
            }
        }
        // wave leader: partial Kabsch sums for its 8 points
        if (lane == 0) {
            double acc[16];
            #pragma unroll
            for (int i = 0; i < 16; i++) acc[i] = 0.0;
            #pragma unroll
            for (int k = 0; k < 8; k++) {
                float4 q4 = t4c[bm[k]];
                float a2 = px[k]*px[k] + py[k]*py[k] + pz[k]*pz[k];
                float d2 = fmaxf(a2 + 2.0f*bs[k], 0.0f);
                double pxd = px[k], pyd = py[k], pzd = pz[k];
                double qxd = q4.x, qyd = q4.y, qzd = q4.z;
                acc[0] += pxd;  acc[1] += pyd;  acc[2] += pzd;
                acc[3] += qxd;  acc[4] += qyd;  acc[5] += qzd;
                acc[6] += pxd*qxd;  acc[7]  += pxd*qyd;  acc[8]  += pxd*qzd;
                acc[9] += pyd*qxd;  acc[10] += pyd*qyd;  acc[11] += pyd*qzd;
                acc[12]+= pzd*qxd;  acc[13] += pzd*qyd;  acc[14] += pzd*qzd;
                acc[15]+= (double)sqrtf(d2);
            }
            #pragma unroll
            for (int i = 0; i < 16; i++) pmem[w][i] = acc[i];
        }
        __syncthreads();
        if (tid < 16)
            part_g[bid * 16 + tid] = pmem[0][tid] + pmem[1][tid] + pmem[2][tid] + pmem[3][tid];
        __syncthreads();

        // ---- grid barrier with last-block election ----
        ++gen;
        if (tid == 0) {
            __threadfence();                               // release part_g
            unsigned int t = atomicAdd(ticket, 1u);
            islast_sh = (t == gen * NBLOCKS - 1u) ? 1 : 0;
        }
        __syncthreads();
        if (islast_sh) {
            __threadfence();                               // acquire others' part_g
            {   // wave w reduces batch w
                int v = lane & 15, c = lane >> 4;
                double ssum = 0.0;
                for (int r = 0; r < 32; r++)
                    ssum += part_g[((w << 7) + (c << 5) + r) * 16 + v];
                ssum += __shfl_xor(ssum, 16);
                ssum += __shfl_xor(ssum, 32);
                if (lane < 16) Ssh[w][lane] = ssum;
            }
            __syncthreads();
            if (tid == 0) {
                bool conv = true;
                float e[BATCH];
                for (int bb = 0; bb < BATCH; bb++) {
                    e[bb] = (float)(Ssh[bb][15] / (double)NPTS);
                    conv = conv && (fabsf(e[bb] - errlast[bb]) < ICP_TOL);
                }
                convsh = conv ? 1 : 0;
                *done_g = conv ? 1 : 0;
                if (!conv)
                    for (int bb = 0; bb < BATCH; bb++) errlast[bb] = e[bb];
            }
            __syncthreads();
            if (tid < BATCH && !convsh) {
                double S[16];
                #pragma unroll
                for (int i = 0; i < 16; i++) S[i] = Ssh[tid][i];
                double R[3][3], t[3];
                kabsch_from_sums(S, R, t);
                float* o = Rt_g + tid * 12;
                o[0] = (float)R[0][0]; o[1]  = (float)R[0][1]; o[2]  = (float)R[0][2];
                o[3] = (float)R[1][0]; o[4]  = (float)R[1][1]; o[5]  = (float)R[1][2];
                o[6] = (float)R[2][0]; o[7]  = (float)R[2][1]; o[8]  = (float)R[2][2];
                o[9] = (float)t[0];    o[10] = (float)t[1];    o[11] = (float)t[2];
            }
            __syncthreads();
            if (tid == 0) {
                __threadfence();                           // release Rt/done/errlast
                atomicAdd(release_g, 1u);
            }
        }
        if (tid == 0) {
            while (__hip_atomic_load(release_g, __ATOMIC_ACQUIRE, __HIP_MEMORY_SCOPE_AGENT) < gen)
                __builtin_amdgcn_s_sleep(2);
        }
        __syncthreads();
        __threadfence();                                   // invalidate L1 before Rt/done reads

        if (*done_g) break;                                // all blocks agree; state frozen

        const float* rt = Rt_g + b * 12;
        float r0=rt[0], r1=rt[1], r2=rt[2], r3=rt[3], r4=rt[4], r5=rt[5];
        float r6=rt[6], r7=rt[7], r8=rt[8], t0=rt[9], t1=rt[10], t2=rt[11];
        #pragma unroll
        for (int k = 0; k < 8; k++) {
            float x = px[k], y = py[k], z = pz[k];
            px[k] = r0*x + r1*y + r2*z + t0;
            py[k] = r3*x + r4*y + r5*z + t1;
            pz[k] = r6*x + r7*y + r8*z + t2;
        }
    }

    // ---- final Kabsch: orig source -> current temporal (identity pairing) ----
    if (lane == 0) {
        double acc[16];
        #pragma unroll
        for (int i = 0; i < 16; i++) acc[i] = 0.0;
        #pragma unroll
        for (int k = 0; k < 8; k++) {
            double pxd = ox[k], pyd = oy[k], pzd = oz[k];
            double qxd = px[k], qyd = py[k], qzd = pz[k];
            acc[0] += pxd;  acc[1] += pyd;  acc[2] += pzd;
            acc[3] += qxd;  acc[4] += qyd;  acc[5] += qzd;
            acc[6] += pxd*qxd;  acc[7]  += pxd*qyd;  acc[8]  += pxd*qzd;
            acc[9] += pyd*qxd;  acc[10] += pyd*qyd;  acc[11] += pyd*qzd;
            acc[12]+= pzd*qxd;  acc[13] += pzd*qyd;  acc[14] += pzd*qzd;
        }
        #pragma unroll
        for (int i = 0; i < 16; i++) pmem[w][i] = acc[i];
    }
    __syncthreads();
    if (tid < 16) {
        double ssum = pmem[0][tid] + pmem[1][tid] + pmem[2][tid] + pmem[3][tid];
        part_g[bid * 16 + tid] = (tid == 15) ? 0.0 : ssum;
    }
    __syncthreads();

    ++gen;
    if (tid == 0) {
        __threadfence();
        unsigned int t = atomicAdd(ticket, 1u);
        islast_sh = (t == gen * NBLOCKS - 1u) ? 1 : 0;
    }
    __syncthreads();
    if (!islast_sh) return;                                // non-elected blocks exit

    __threadfence();
    {
        int v = lane & 15, c = lane >> 4;
        double ssum = 0.0;
        for (int r = 0; r < 32; r++)
            ssum += part_g[((w << 7) + (c << 5) + r) * 16 + v];
        ssum += __shfl_xor(ssum, 16);
        ssum += __shfl_xor(ssum, 32);
        if (lane < 16) Ssh[w][lane] = ssum;
    }
    __syncthreads();
    if (tid < BATCH) {
        double S[16];
        #pragma unroll
        for (int i = 0; i < 16; i++) S[i] = Ssh[tid][i];
        double R[3][3], t[3];
        kabsch_from_sums(S, R, t);
        float* o = out + tid * 12;
        #pragma unroll
        for (int i = 0; i < 3; i++) {
            o[i*4+0] = (float)R[i][0];
            o[i*4+1] = (float)R[i][1];
            o[i*4+2] = (float)R[i][2];
            o[i*4+3] = (float)t[i];
        }
    }
}

// ----------------------------- launcher -----------------------------

extern "C" void kernel_launch(void* const* d_in, const int* in_sizes, int n_in,
                              void* d_out, int out_size, void* d_ws, size_t ws_size,
                              hipStream_t stream) {
    const float* src = (const float*)d_in[0];
    const float* tgt = (const float*)d_in[1];
    float* out = (float*)d_out;

    char* ws = (char*)d_ws;
    double* part_g  = (double*)ws;                         // 512*16*8 = 65536 B
    float*  Rt_g    = (float*)(ws + 65536);                // 192 B
    float*  errlast = (float*)(ws + 65792);                // 16 B
    int*    done_g  = (int*)(ws + 65808);                  // 4 B
    unsigned int* ticket    = (unsigned int*)(ws + 65812); // 4 B
    unsigned int* release_g = (unsigned int*)(ws + 65816); // 4 B

    k_init<<<dim3(1), dim3(64), 0, stream>>>(errlast, done_g, ticket, release_g);
    k_icp<<<dim3(NBLOCKS), dim3(TPB), 0, stream>>>(src, tgt, out, part_g, Rt_g,
                                                   errlast, done_g, ticket, release_g);
}

// Round 5
// 442.628 us; speedup vs baseline: 3.9794x; 3.9794x over previous
//
#include <hip/hip_runtime.h>

#define BATCH   4
#define NPTS    4096
#define MPTS    4096
#define NSTEPS  16
#define ICP_TOL 1e-6f

#define TPB        512
#define NBLOCKS    256       // 64 blocks/batch x 4; grid <= 256 CUs -> all resident
#define BLK_PER_B  64
// LDS ~66.7 KB/block, VGPR capped <=256 by 512-thread block -> 1 block/CU fits.

// Workspace layout (bytes):
//   accD : 16 steps x 4 batches x 16 values, one 64B line per value  = 65536
//   cntU : 16 x 4 counters, one 64B line each                        =  4096
//   MstF : 16 x 4 x 16 floats {err, m00..m22, t0..t2, pad}           =  4096
#define ACC_OFF 0
#define CNT_OFF 65536
#define MST_OFF 69632
#define ZERO_DWORDS (69632/4)

// ---------- 3x3 Kabsch from sums: fp64 arithmetic, fp32 HW trig ----------

__device__ inline void normalize3d(double v[3]) {
    double n = sqrt(v[0]*v[0] + v[1]*v[1] + v[2]*v[2]);
    double inv = (n > 1e-300) ? 1.0 / n : 0.0;
    v[0] *= inv; v[1] *= inv; v[2] *= inv;
}

__device__ inline void cross3d(const double a[3], const double b[3], double c[3]) {
    c[0] = a[1]*b[2] - a[2]*b[1];
    c[1] = a[2]*b[0] - a[0]*b[2];
    c[2] = a[0]*b[1] - a[1]*b[0];
}

// eigenvector of K for the eigenvalue NOT in {la, lb}: any nonzero column of
// (K - la I)(K - lb I) (spectral projector).
__device__ inline void eigvec_from_product(const double K[3][3], double la, double lb, double v[3]) {
    double A[3][3], Bm[3][3], C[3][3];
    #pragma unroll
    for (int i = 0; i < 3; i++)
        #pragma unroll
        for (int j = 0; j < 3; j++) {
            A[i][j]  = K[i][j] - ((i == j) ? la : 0.0);
            Bm[i][j] = K[i][j] - ((i == j) ? lb : 0.0);
        }
    #pragma unroll
    for (int i = 0; i < 3; i++)
        #pragma unroll
        for (int j = 0; j < 3; j++) {
            double s = 0.0;
            #pragma unroll
            for (int k = 0; k < 3; k++) s += A[i][k] * Bm[k][j];
            C[i][j] = s;
        }
    int best = 0; double bn = -1.0;
    #pragma unroll
    for (int c = 0; c < 3; c++) {
        double n2 = C[0][c]*C[0][c] + C[1][c]*C[1][c] + C[2][c]*C[2][c];
        if (n2 > bn) { bn = n2; best = c; }
    }
    if (bn > 1e-280) {
        double inv = 1.0 / sqrt(bn);
        v[0] = C[0][best]*inv; v[1] = C[1][best]*inv; v[2] = C[2][best]*inv;
    } else {
        v[0] = 1.0; v[1] = 0.0; v[2] = 0.0;
    }
}

__device__ inline void kabsch_from_sums(const double S[16], double R[3][3], double t[3]) {
    const double inv_n = 1.0 / (double)NPTS;
    double cs[3] = { S[0]*inv_n, S[1]*inv_n, S[2]*inv_n };
    double ct[3] = { S[3]*inv_n, S[4]*inv_n, S[5]*inv_n };
    double H[3][3];
    #pragma unroll
    for (int i = 0; i < 3; i++)
        #pragma unroll
        for (int j = 0; j < 3; j++)
            H[i][j] = S[6 + 3*i + j] - S[i]*S[3 + j]*inv_n;

    double K[3][3];
    #pragma unroll
    for (int i = 0; i < 3; i++)
        #pragma unroll
        for (int j = 0; j < 3; j++) {
            double s = 0.0;
            #pragma unroll
            for (int k = 0; k < 3; k++) s += H[k][i]*H[k][j];
            K[i][j] = s;
        }

    double q = (K[0][0] + K[1][1] + K[2][2]) / 3.0;
    double p1 = K[0][1]*K[0][1] + K[0][2]*K[0][2] + K[1][2]*K[1][2];
    double a00 = K[0][0]-q, a11 = K[1][1]-q, a22 = K[2][2]-q;
    double p2 = a00*a00 + a11*a11 + a22*a22 + 2.0*p1;
    double p = sqrt(p2 / 6.0);
    double l1, l2, l3;
    if (p < 1e-150) {
        l1 = l2 = l3 = q;
    } else {
        double ip = 1.0 / p;
        double b00 = a00*ip, b01 = K[0][1]*ip, b02 = K[0][2]*ip;
        double b11 = a11*ip, b12 = K[1][2]*ip, b22 = a22*ip;
        double detB = b00*(b11*b22 - b12*b12)
                    - b01*(b01*b22 - b12*b02)
                    + b02*(b01*b12 - b11*b02);
        double r = 0.5 * detB;
        r = r < -1.0 ? -1.0 : (r > 1.0 ? 1.0 : r);
        // fp32 HW trig: phi error ~1e-7 rad; projector method tolerates it
        float phi = acosf((float)r) * (1.0f/3.0f);
        l1 = q + 2.0*p*(double)cosf(phi);
        l3 = q + 2.0*p*(double)cosf(phi + 2.0943951f); // +2pi/3
        l2 = 3.0*q - l1 - l3;
    }

    double v1[3], v2[3], v3[3];
    eigvec_from_product(K, l2, l3, v1);
    eigvec_from_product(K, l1, l3, v2);
    double d12 = v1[0]*v2[0] + v1[1]*v2[1] + v1[2]*v2[2];
    #pragma unroll
    for (int i = 0; i < 3; i++) v2[i] -= d12*v1[i];
    normalize3d(v2);
    cross3d(v1, v2, v3);

    double u1[3], u2[3], u3[3];
    #pragma unroll
    for (int i = 0; i < 3; i++) u1[i] = H[i][0]*v1[0] + H[i][1]*v1[1] + H[i][2]*v1[2];
    normalize3d(u1);
    #pragma unroll
    for (int i = 0; i < 3; i++) u2[i] = H[i][0]*v2[0] + H[i][1]*v2[1] + H[i][2]*v2[2];
    double du = u1[0]*u2[0] + u1[1]*u2[1] + u1[2]*u2[2];
    #pragma unroll
    for (int i = 0; i < 3; i++) u2[i] -= du*u1[i];
    normalize3d(u2);
    cross3d(u1, u2, u3);

    #pragma unroll
    for (int i = 0; i < 3; i++)
        #pragma unroll
        for (int j = 0; j < 3; j++)
            R[i][j] = v1[i]*u1[j] + v2[i]*u2[j] + v3[i]*u3[j];
    #pragma unroll
    for (int i = 0; i < 3; i++)
        t[i] = ct[i] - (R[i][0]*cs[0] + R[i][1]*cs[1] + R[i][2]*cs[2]);
}

// ------------------------------- kernels -------------------------------

__global__ void k_init(unsigned int* __restrict__ wsz) {
    int i = blockIdx.x * blockDim.x + threadIdx.x;
    if (i < ZERO_DWORDS) wsz[i] = 0u;
}

// Persistent per-batch ICP: 64 blocks per batch, fence-free atomic barrier.
__global__ __launch_bounds__(TPB)
void k_icp(const float* __restrict__ src, const float* __restrict__ tgt,
           double* __restrict__ accD, unsigned int* __restrict__ cntU,
           float* __restrict__ MstF) {
    __shared__ float4 t4c[MPTS];      // 64 KB: (x,y,z, 0.5*|t|^2), resident all steps
    __shared__ double pmem[8][16];    // per-wave partial sums
    __shared__ double Ssh[16];        // batch sums (broadcast)

    const int bid  = blockIdx.x;
    const int b    = bid >> 6;              // batch
    const int lb   = bid & (BLK_PER_B - 1);
    const int tid  = threadIdx.x;
    const int w    = tid >> 6;              // wave 0..7, owns 8 points
    const int lane = tid & 63;

    const float* tgb = tgt + (size_t)b * MPTS * 3;
    const float* spb = src + ((size_t)b * NPTS + lb * 64 + w * 8) * 3;

    // stage ALL targets into LDS once
    for (int i = tid; i < MPTS; i += TPB) {
        float x = tgb[3*i], y = tgb[3*i+1], z = tgb[3*i+2];
        t4c[i] = make_float4(x, y, z, 0.5f*(x*x + y*y + z*z));
    }

    float px[8], py[8], pz[8];
    #pragma unroll
    for (int k = 0; k < 8; k++) {
        px[k] = spb[3*k+0]; py[k] = spb[3*k+1]; pz[k] = spb[3*k+2];
    }
    // composed transform M (uniform across threads of a batch)
    float m00=1.f,m01=0.f,m02=0.f, m10=0.f,m11=1.f,m12=0.f, m20=0.f,m21=0.f,m22=1.f;
    float mt0=0.f,mt1=0.f,mt2=0.f;
    __syncthreads();

    for (int s = 0; s < NSTEPS; ++s) {
        // ---- 1-NN scan: score = 0.5|t|^2 - p.t (d2 = |p|^2 + 2*score) ----
        float bs[8]; int bm[8];
        #pragma unroll
        for (int k = 0; k < 8; k++) { bs[k] = 1e30f; bm[k] = 0; }

        #pragma unroll 4
        for (int j = 0; j < MPTS/64; ++j) {
            int ml = (j << 6) | lane;
            float4 T = t4c[ml];
            #pragma unroll
            for (int k = 0; k < 8; k++) {
                float sc = __fmaf_rn(-px[k], T.x, T.w);
                sc = __fmaf_rn(-py[k], T.y, sc);
                sc = __fmaf_rn(-pz[k], T.z, sc);
                if (sc < bs[k]) { bs[k] = sc; bm[k] = ml; }   // first-min per lane
            }
        }
        // 64-lane butterfly argmin, exact first-min (smallest index) tie rule
        #pragma unroll
        for (int off = 32; off >= 1; off >>= 1) {
            #pragma unroll
            for (int k = 0; k < 8; k++) {
                float os = __shfl_xor(bs[k], off);
                int   om = __shfl_xor(bm[k], off);
                if (os < bs[k] || (os == bs[k] && om < bm[k])) { bs[k] = os; bm[k] = om; }
            }
        }
        // wave leader: partial Kabsch sums over its 8 points
        if (lane == 0) {
            double acc[16];
            #pragma unroll
            for (int i = 0; i < 16; i++) acc[i] = 0.0;
            #pragma unroll
            for (int k = 0; k < 8; k++) {
                float4 q4 = t4c[bm[k]];
                float a2 = px[k]*px[k] + py[k]*py[k] + pz[k]*pz[k];
                float d2 = fmaxf(a2 + 2.0f*bs[k], 0.0f);
                double pxd = px[k], pyd = py[k], pzd = pz[k];
                double qxd = q4.x, qyd = q4.y, qzd = q4.z;
                acc[0] += pxd;  acc[1] += pyd;  acc[2] += pzd;
                acc[3] += qxd;  acc[4] += qyd;  acc[5] += qzd;
                acc[6] += pxd*qxd;  acc[7]  += pxd*qyd;  acc[8]  += pxd*qzd;
                acc[9] += pyd*qxd;  acc[10] += pyd*qyd;  acc[11] += pyd*qzd;
                acc[12]+= pzd*qxd;  acc[13] += pzd*qyd;  acc[14] += pzd*qzd;
                acc[15]+= (double)sqrtf(d2);
            }
            #pragma unroll
            for (int i = 0; i < 16; i++) pmem[w][i] = acc[i];
        }
        __syncthreads();

        const int slot = (s * BATCH + b) * 16;
        if (tid < 16) {
            double v = pmem[0][tid] + pmem[1][tid] + pmem[2][tid] + pmem[3][tid]
                     + pmem[4][tid] + pmem[5][tid] + pmem[6][tid] + pmem[7][tid];
            unsafeAtomicAdd(&accD[(size_t)(slot + tid) * 8], v);   // f64 HW atomic @ IC
        }
        // drain the adds to the coherence point before announcing arrival
        asm volatile("s_waitcnt vmcnt(0)" ::: "memory");
        if (tid == 0) {
            unsigned int* cp = &cntU[(size_t)(s * BATCH + b) * 16];
            __hip_atomic_fetch_add(cp, 1u, __ATOMIC_RELAXED, __HIP_MEMORY_SCOPE_AGENT);
            while (__hip_atomic_load(cp, __ATOMIC_ACQUIRE, __HIP_MEMORY_SCOPE_AGENT) < BLK_PER_B)
                __builtin_amdgcn_s_sleep(16);   // ~1024 cyc backoff: low poll traffic
        }
        if (tid < 16)
            Ssh[tid] = __hip_atomic_load(&accD[(size_t)(slot + tid) * 8],
                                         __ATOMIC_RELAXED, __HIP_MEMORY_SCOPE_AGENT);
        __syncthreads();

        // ---- uniform (redundant) Kabsch from batch sums ----
        double S[16];
        #pragma unroll
        for (int i = 0; i < 16; i++) S[i] = Ssh[i];
        float errnew = (float)(S[15] * (1.0 / (double)NPTS));
        double R[3][3], t[3];
        kabsch_from_sums(S, R, t);
        float r00=(float)R[0][0], r01=(float)R[0][1], r02=(float)R[0][2];
        float r10=(float)R[1][0], r11=(float)R[1][1], r12=(float)R[1][2];
        float r20=(float)R[2][0], r21=(float)R[2][1], r22=(float)R[2][2];
        float t0=(float)t[0], t1=(float)t[1], t2=(float)t[2];

        // transform own points
        #pragma unroll
        for (int k = 0; k < 8; k++) {
            float x = px[k], y = py[k], z = pz[k];
            px[k] = r00*x + r01*y + r02*z + t0;
            py[k] = r10*x + r11*y + r12*z + t1;
            pz[k] = r20*x + r21*y + r22*z + t2;
        }
        // compose M_s = T_s o M_{s-1}
        float n00 = r00*m00 + r01*m10 + r02*m20;
        float n01 = r00*m01 + r01*m11 + r02*m21;
        float n02 = r00*m02 + r01*m12 + r02*m22;
        float n10 = r10*m00 + r11*m10 + r12*m20;
        float n11 = r10*m01 + r11*m11 + r12*m21;
        float n12 = r10*m02 + r11*m12 + r12*m22;
        float n20 = r20*m00 + r21*m10 + r22*m20;
        float n21 = r20*m01 + r21*m11 + r22*m21;
        float n22 = r20*m02 + r21*m12 + r22*m22;
        float nt0 = r00*mt0 + r01*mt1 + r02*mt2 + t0;
        float nt1 = r10*mt0 + r11*mt1 + r12*mt2 + t1;
        float nt2 = r20*mt0 + r21*mt1 + r22*mt2 + t2;
        m00=n00; m01=n01; m02=n02; m10=n10; m11=n11; m12=n12;
        m20=n20; m21=n21; m22=n22; mt0=nt0; mt1=nt1; mt2=nt2;

        // record err_s and M_s (plain stores; read next dispatch)
        if (lb == 0 && tid == 0) {
            float* o = MstF + (size_t)(s * BATCH + b) * 16;
            o[0] = errnew;
            o[1] = m00; o[2] = m01; o[3] = m02;
            o[4] = m10; o[5] = m11; o[6] = m12;
            o[7] = m20; o[8] = m21; o[9] = m22;
            o[10] = mt0; o[11] = mt1; o[12] = mt2;
        }
    }
}

// Final selection: T = first step where all batches' |err_s - err_{s-1}| < tol;
// output M_{T-1} (identity if T==1), else M_16.  out layout [B,3,4] = [R|t].
__global__ void k_final(const float* __restrict__ MstF, float* __restrict__ out) {
    const int lane = threadIdx.x;   // 64 threads, computation uniform
    float ep0 = 0.f, ep1 = 0.f, ep2 = 0.f, ep3 = 0.f;
    int sel = NSTEPS - 1;           // default: slot 15 = M_16
    bool ident = false;
    bool found = false;
    for (int s = 0; s < NSTEPS && !found; ++s) {
        float e0 = MstF[(s*4+0)*16], e1 = MstF[(s*4+1)*16];
        float e2 = MstF[(s*4+2)*16], e3 = MstF[(s*4+3)*16];
        if (fabsf(e0-ep0) < ICP_TOL && fabsf(e1-ep1) < ICP_TOL &&
            fabsf(e2-ep2) < ICP_TOL && fabsf(e3-ep3) < ICP_TOL) {
            found = true;
            if (s == 0) ident = true; else sel = s - 1;
        } else {
            ep0 = e0; ep1 = e1; ep2 = e2; ep3 = e3;
        }
    }
    if (lane < BATCH) {
        float* o = out + lane * 12;
        if (ident) {
            o[0]=1.f; o[1]=0.f; o[2]=0.f; o[3]=0.f;
            o[4]=0.f; o[5]=1.f; o[6]=0.f; o[7]=0.f;
            o[8]=0.f; o[9]=0.f; o[10]=1.f; o[11]=0.f;
        } else {
            const float* m = MstF + (size_t)(sel*4 + lane) * 16;
            o[0]=m[1];  o[1]=m[2];  o[2]=m[3];  o[3]=m[10];
            o[4]=m[4];  o[5]=m[5];  o[6]=m[6];  o[7]=m[11];
            o[8]=m[7];  o[9]=m[8];  o[10]=m[9]; o[11]=m[12];
        }
    }
}

// ----------------------------- launcher -----------------------------

extern "C" void kernel_launch(void* const* d_in, const int* in_sizes, int n_in,
                              void* d_out, int out_size, void* d_ws, size_t ws_size,
                              hipStream_t stream) {
    const float* src = (const float*)d_in[0];
    const float* tgt = (const float*)d_in[1];
    float* out = (float*)d_out;

    char* ws = (char*)d_ws;
    double*       accD = (double*)(ws + ACC_OFF);
    unsigned int* cntU = (unsigned int*)(ws + CNT_OFF);
    float*        MstF = (float*)(ws + MST_OFF);

    k_init<<<dim3((ZERO_DWORDS + 255)/256), dim3(256), 0, stream>>>((unsigned int*)ws);
    k_icp<<<dim3(NBLOCKS), dim3(TPB), 0, stream>>>(src, tgt, accD, cntU, MstF);
    k_final<<<dim3(1), dim3(64), 0, stream>>>(MstF, out);
}